// Round 5
// baseline (138.138 us; speedup 1.0000x reference)
//
#include <hip/hip_runtime.h>
#include <hip/hip_bf16.h>
#include <math.h>

#define BS 16
#define Q 1024
#define CC 92
#define T 128
#define M 1024   // columns in transposed problem (= Q)
#define NR 128   // rows in transposed problem (= T)
#define NQB 16   // q-blocks of 64 per batch
#define KTOP 64  // per-row candidate list length (one entry per lane)

// ---------------------------------------------------------------------------
// Fused prep kernel: one block per (b, 64-q slab). Bit-identical Cb.
// ---------------------------------------------------------------------------
__global__ __launch_bounds__(256) void prep_kernel(
    const float* __restrict__ logits,   // [BS][Q][CC]
    const float* __restrict__ ppts,     // [BS][Q][2]
    const int*   __restrict__ tlab,     // [BS][T]
    const float* __restrict__ tpts,     // [BS][T][2]
    float* __restrict__ Cb,             // [BS][Q][T]
    float* __restrict__ CbT,            // [BS][NR][Q]
    unsigned long long* __restrict__ part)  // [BS][NQB][NR]
{
    const int blk = blockIdx.x;         // 0..BS*NQB-1
    const int b   = blk & 15;           // XCD swizzle: blk%8 == b%8
    const int qb  = blk >> 4;
    const int q0  = qb * 64;
    const int tid = threadIdx.x;
    const int lane = tid & 63;

    __shared__ float lg[64 * CC];       // logits slab, [ql][c]
    __shared__ float tile[128][68];     // [t][ql], pitch 68 for b128 align
    __shared__ float tx_sh[T], ty_sh[T];
    __shared__ int   lab_sh[T];
    __shared__ float mx_sh[64], inv_sh[64], px_sh[64], py_sh[64];

    if (tid < T) {
        lab_sh[tid] = tlab[b * T + tid];
        tx_sh[tid]  = tpts[(b * T + tid) * 2 + 0];
        ty_sh[tid]  = tpts[(b * T + tid) * 2 + 1];
    }
    if (tid < 64) {
        px_sh[tid] = ppts[((size_t)b * Q + q0 + tid) * 2 + 0];
        py_sh[tid] = ppts[((size_t)b * Q + q0 + tid) * 2 + 1];
    }
    const float* lbase = logits + ((size_t)b * Q + q0) * CC;
    for (int idx = tid; idx < 64 * CC; idx += 256) lg[idx] = lbase[idx];
    __syncthreads();

    // softmax stats: EXACT same op sequence as original cost kernel.
    {
        const int w = tid >> 6;
        for (int s = 0; s < 16; ++s) {
            const int ql = w * 16 + s;
            const float* c = &lg[ql * CC];
            float l0 = c[lane];
            float l1 = (lane + 64 < CC) ? c[lane + 64] : -INFINITY;
            float mx = fmaxf(l0, l1);
            #pragma unroll
            for (int off = 32; off > 0; off >>= 1)
                mx = fmaxf(mx, __shfl_down(mx, off));
            mx = __shfl(mx, 0);
            float es = expf(l0 - mx) + ((lane + 64 < CC) ? expf(l1 - mx) : 0.0f);
            #pragma unroll
            for (int off = 32; off > 0; off >>= 1) es += __shfl_down(es, off);
            es = __shfl(es, 0);
            if (lane == 0) { mx_sh[ql] = mx; inv_sh[ql] = 1.0f / es; }
        }
    }
    __syncthreads();

    // tile compute + Cb write: thread = (ql = tid>>2, tc = tid&3)
    {
        const int ql = tid >> 2;
        const int tc = tid & 3;
        const float px = px_sh[ql], py = py_sh[ql];
        const float mx = mx_sh[ql], inv = inv_sh[ql];
        const float* lgq = &lg[ql * CC];
        float* cbrow = Cb + ((size_t)b * Q + q0 + ql) * T + tc * 32;
        #pragma unroll
        for (int k = 0; k < 8; ++k) {
            float4 o;
            #pragma unroll
            for (int e = 0; e < 4; ++e) {
                const int t = tc * 32 + 4 * k + e;
                const int labv = lab_sh[t];
                float prob = expf(lgq[labv] - mx) * inv;
                float cp   = fabsf(px - tx_sh[t]) + fabsf(py - ty_sh[t]);
                float val  = cp - prob;
                (&o.x)[e] = val;
                tile[t][ql] = val;
            }
            ((float4*)cbrow)[k] = o;
        }
    }
    __syncthreads();

    // CbT write + rowmin partials: thread = (rg = tid>>4, c4 = tid&15)
    {
        const int rg = tid >> 4;
        const int c4 = tid & 15;
        #pragma unroll
        for (int it = 0; it < 8; ++it) {
            const int t = it * 16 + rg;
            float4 v = *(const float4*)&tile[t][4 * c4];
            *(float4*)(CbT + ((size_t)b * NR + t) * Q + q0 + 4 * c4) = v;

            unsigned long long bk = ~0ull;
            const float* vf = (const float*)&v;
            #pragma unroll
            for (int e = 0; e < 4; ++e) {
                unsigned bits = __float_as_uint(vf[e]);
                unsigned mono = (bits & 0x80000000u) ? ~bits
                                                     : (bits | 0x80000000u);
                const int j = q0 + 4 * c4 + e;
                unsigned long long key =
                    ((unsigned long long)mono << 10) | (unsigned)j;
                bk = (key < bk) ? key : bk;
            }
            #pragma unroll
            for (int off = 1; off < 16; off <<= 1) {
                unsigned long long ok = __shfl_xor(bk, off);
                bk = (ok < bk) ? ok : bk;
            }
            if (c4 == 0) part[((size_t)b * NQB + qb) * NR + t] = bk;
        }
    }
}

// ---------------------------------------------------------------------------
// Fallback cost kernel (only used if workspace is too small).
// ---------------------------------------------------------------------------
__global__ __launch_bounds__(256) void cost_kernel(
    const float* __restrict__ logits, const float* __restrict__ ppts,
    const int* __restrict__ tlab, const float* __restrict__ tpts,
    float* __restrict__ Cb)
{
    const int blk  = blockIdx.x;
    const int b    = blk >> 8;
    const int wave = threadIdx.x >> 6;
    const int lane = threadIdx.x & 63;
    const int q    = (blk & 255) * 4 + wave;

    __shared__ float tx_sh[T], ty_sh[T];
    __shared__ int   lab_sh[T];
    __shared__ float logit_sh[4][CC];

    if (threadIdx.x < T) {
        lab_sh[threadIdx.x] = tlab[b * T + threadIdx.x];
        tx_sh[threadIdx.x]  = tpts[(b * T + threadIdx.x) * 2 + 0];
        ty_sh[threadIdx.x]  = tpts[(b * T + threadIdx.x) * 2 + 1];
    }
    const float* lrow = logits + ((size_t)b * Q + q) * CC;
    float l0 = lrow[lane];
    float l1 = (lane + 64 < CC) ? lrow[lane + 64] : -INFINITY;
    logit_sh[wave][lane] = l0;
    if (lane + 64 < CC) logit_sh[wave][lane + 64] = l1;

    float mx = fmaxf(l0, l1);
    #pragma unroll
    for (int off = 32; off > 0; off >>= 1) mx = fmaxf(mx, __shfl_down(mx, off));
    mx = __shfl(mx, 0);
    float es = expf(l0 - mx) + ((lane + 64 < CC) ? expf(l1 - mx) : 0.0f);
    #pragma unroll
    for (int off = 32; off > 0; off >>= 1) es += __shfl_down(es, off);
    es = __shfl(es, 0);
    const float inv = 1.0f / es;
    const float px = ppts[((size_t)b * Q + q) * 2 + 0];
    const float py = ppts[((size_t)b * Q + q) * 2 + 1];
    __syncthreads();
    float* outrow = Cb + ((size_t)b * Q + q) * T;
    #pragma unroll
    for (int t = lane; t < T; t += 64) {
        int   labv = lab_sh[t];
        float prob = expf(logit_sh[wave][labv] - mx) * inv;
        float cp   = fabsf(px - tx_sh[t]) + fabsf(py - ty_sh[t]);
        outrow[t]  = cp - prob;
    }
}

// DPP wave64 umin reduce step: dest = min(x, x shifted by ctrl); OOB lanes
// keep old (= x), so they're no-ops. Self-merge is idempotent for pure min
// — this reduce is EXACT.
#define DPP_UMIN_STEP(x, ctrl)                                              \
    {                                                                       \
        unsigned _t = (unsigned)__builtin_amdgcn_update_dpp(                \
            (int)(x), (int)(x), (ctrl), 0xF, 0xF, false);                   \
        (x) = ((x) < _t) ? (x) : _t;                                        \
    }

#define DPP_UMIN_REDUCE(x)                                                  \
    DPP_UMIN_STEP(x, 0x111); DPP_UMIN_STEP(x, 0x112);                       \
    DPP_UMIN_STEP(x, 0x114); DPP_UMIN_STEP(x, 0x118);                       \
    DPP_UMIN_STEP(x, 0x142); DPP_UMIN_STEP(x, 0x143);

__device__ __forceinline__ unsigned mono_enc(float f) {
    unsigned b = __float_as_uint(f);
    return (b & 0x80000000u) ? ~b : (b | 0x80000000u);
}
__device__ __forceinline__ float mono_dec(unsigned m) {
    unsigned b = (m & 0x80000000u) ? (m ^ 0x80000000u) : ~m;
    return __uint_as_float(b);
}

// ---------------------------------------------------------------------------
// topk kernel: one WAVE per (b, row). Builds the exact KTOP=64 smallest RAW
// costs of each CbT row (by packed key (mono(c)&~1023)|j: 22 cost bits + 10
// col bits) plus the provable threshold tau = bucket floor of the 64th key:
// every column NOT in the list has c >= tau (exact, monotone-code argument;
// no fp margin needed). Runs at full occupancy — this is the parallelism
// the latency-bound solver can't use itself.
// ---------------------------------------------------------------------------
__global__ __launch_bounds__(256) void topk_kernel(
    const float* __restrict__ CbT,   // [BS*NR][Q]
    float2* __restrict__ topk,       // [BS*NR][KTOP] = (raw c, j-as-int)
    float* __restrict__ tauv)        // [BS*NR]
{
    const int wave = threadIdx.x >> 6;
    const int lane = threadIdx.x & 63;
    const int row  = blockIdx.x * 4 + wave;   // 0..BS*NR-1

    const float4* rp = (const float4*)(CbT + (size_t)row * Q);
    unsigned kk[16];
    #pragma unroll
    for (int g = 0; g < 4; ++g) {
        const float4 c4 = rp[lane + 64 * g];
        const float* cf = (const float*)&c4;
        #pragma unroll
        for (int e = 0; e < 4; ++e) {
            const int j = 256 * g + 4 * lane + e;
            kk[4 * g + e] = (mono_enc(cf[e]) & 0xFFFFFC00u) | (unsigned)j;
        }
    }

    // KTOP rounds of global extract-min; lane r keeps the r-th smallest key.
    unsigned mykey = 0xFFFFFFFFu;
    for (int r = 0; r < KTOP; ++r) {
        unsigned lm = kk[0];
        #pragma unroll
        for (int e = 1; e < 16; ++e) lm = (kk[e] < lm) ? kk[e] : lm;
        unsigned rm = lm;
        DPP_UMIN_REDUCE(rm);
        const unsigned g = (unsigned)__builtin_amdgcn_readlane((int)rm, 63);
        #pragma unroll
        for (int e = 0; e < 16; ++e) if (kk[e] == g) kk[e] = 0xFFFFFFFFu;
        if (lane == r) mykey = g;
    }

    {
        const int jj = (int)(mykey & 1023u);
        const float c = CbT[(size_t)row * Q + jj];   // exact RAW fp32 cost
        topk[(size_t)row * KTOP + lane] = make_float2(c, __int_as_float(jj));
    }
    if (lane == KTOP - 1) tauv[row] = mono_dec(mykey & 0xFFFFFC00u);
}

// ---------------------------------------------------------------------------
// Kernel 2: JV solver. ONE WAVE per batch.
// Phase A: rowmin-greedy init (exactly tight: fl(c-u)=0 at argmin, v=0).
// Phase B: ART with per-row top-64 LDS fast path (valid when m2 <
// fl(tau-u): v<=0 makes every non-list r = fl(fl(c-u)-v) >= fl(c-u) >=
// fl(tau-u), all monotone-exact). m1/m2 exact via two-stage reduce.
// Phase C: fp32 Dijkstra with a 1-hop fast exit; dense otherwise.
// ---------------------------------------------------------------------------
template<int USET>
__global__ __launch_bounds__(64) void solve_kernel(
    const float* __restrict__ Cb,    // [BS][Q][T] fallback (strided)
    const float* __restrict__ CbT,   // [BS][NR][Q] row-major solver cost
    const unsigned long long* __restrict__ part,  // [BS][NQB][NR] or nullptr
    const float2* __restrict__ topk, // [BS][NR][KTOP] or nullptr
    const float* __restrict__ tauv,  // [BS][NR] or nullptr
    float* __restrict__ out_rows,    // [BS][T]
    float* __restrict__ out_cols)    // [BS][T]
{
    const int b    = blockIdx.x;
    const int lane = threadIdx.x;    // 0..63

    __shared__ int    row4col[M];    // col j -> row (-1 free)
    __shared__ int    col4row[NR];   // row i -> col (-1 free)
    __shared__ float  u_sh[NR];
    __shared__ int    path_lds[M];   // swizzled: A(j) = 256g + 64e + L
    __shared__ int    SRr[NR];       // rows that joined SR (excl. curRow)
    __shared__ float  SRd[NR];       // dist at which they joined
    __shared__ int    minj_sh[NR];   // per-row argmin column
    __shared__ int    claim[M];      // col j -> lowest row claiming it
    __shared__ float2 top_lds[NR * KTOP];  // per-row candidate lists (64 KB)
    __shared__ float  v_lds[M];      // mirror of distributed v_ (fast path)
    __shared__ float  tau_lds[NR];   // per-row non-list lower bound

    const float* CbB  = Cb  + (size_t)b * Q * T;
    const float* CbTB = CbT + (size_t)b * NR * Q;

    for (int j = lane; j < M;  j += 64) { row4col[j] = -1; claim[j] = 0x7fffffff; }
    for (int i = lane; i < NR; i += 64) col4row[i] = -1;

    if (USET) {
        // vectorized list load: 2 entries (16B) per lane-iter
        const float4* tsrc4 = (const float4*)(topk + (size_t)b * NR * KTOP);
        float4* tdst4 = (float4*)top_lds;
        for (int i = lane; i < NR * KTOP / 2; i += 64) tdst4[i] = tsrc4[i];
        for (int j = lane; j < M; j += 64) v_lds[j] = 0.0f;
        for (int i = lane; i < NR; i += 64) tau_lds[i] = tauv[(size_t)b * NR + i];
    }

    // decode rowmin partials (coalesced: lane-consecutive in r)
    if (part) {
        #pragma unroll
        for (int r2 = 0; r2 < 2; ++r2) {
            const int r = lane + 64 * r2;
            const unsigned long long* pr = part + (size_t)b * NQB * NR + r;
            unsigned long long k = pr[0];
            #pragma unroll
            for (int i = 1; i < NQB; ++i) {
                unsigned long long o = pr[(size_t)i * NR];
                k = (o < k) ? o : k;
            }
            minj_sh[r] = (int)(k & 1023u);
            u_sh[r] = mono_dec((unsigned)(k >> 10));
        }
    } else {
        for (int i = lane; i < NR; i += 64) { minj_sh[i] = -1; u_sh[i] = 0.0f; }
    }
    __syncthreads();

    // greedy: lowest row index wins its argmin column
    if (part) {
        #pragma unroll
        for (int r2 = 0; r2 < 2; ++r2) {
            const int r = lane + 64 * r2;
            atomicMin(&claim[minj_sh[r]], r);
        }
        __syncthreads();
        #pragma unroll
        for (int r2 = 0; r2 < 2; ++r2) {
            const int r = lane + 64 * r2;
            const int mj = minj_sh[r];
            if (claim[mj] == r) { col4row[r] = mj; row4col[mj] = r; }
        }
        __syncthreads();
    }

    const float FINF = INFINITY;
    float v_[16], dist_[16];
    #pragma unroll
    for (int k = 0; k < 16; ++k) v_[k] = 0.0f;

    // ---------------- Phase B: augmenting row reduction ------------------
    {
        unsigned long long am0 = ~__ballot(col4row[lane] >= 0);
        unsigned long long am1 = ~__ballot(col4row[lane + 64] >= 0);
        for (int half = 0; half < 2; ++half) {
            unsigned long long mask = half ? am1 : am0;
            while (mask) {
                int cur = __ffsll(mask) - 1 + 64 * half;
                mask &= mask - 1;

                for (int step = 0; step < 48; ++step) {
                    const float ucur = u_sh[cur];
                    float m1, m2; int j1, disp;
                    bool fast = false;

                    if (USET) {
                        // ---- top-64 LDS fast path (one entry per lane) ----
                        const float2 te = top_lds[cur * KTOP + lane];
                        const int    ej = __float_as_int(te.y);
                        const float  vv = v_lds[ej];
                        const float  rr = (te.x - ucur) - vv;  // == dense expr
                        const unsigned key = mono_enc(rr);
                        const int candf = row4col[ej];         // speculative
                        // stage 1: exact min
                        unsigned e1 = key;
                        DPP_UMIN_REDUCE(e1);
                        const unsigned g1 =
                            (unsigned)__builtin_amdgcn_readlane((int)e1, 63);
                        const unsigned long long bm = __ballot(key == g1);
                        const int w = __ffsll(bm) - 1;
                        // stage 2: exact 2nd-min (exclude the winner's entry)
                        unsigned e2 = (lane == w) ? 0xFFFFFFFFu : key;
                        DPP_UMIN_REDUCE(e2);
                        const unsigned g2 =
                            (unsigned)__builtin_amdgcn_readlane((int)e2, 63);
                        const float lim = tau_lds[cur] - ucur;
                        const float f2  = mono_dec(g2);
                        if (f2 < lim) {   // non-list r >= lim > m2 >= m1
                            fast = true;
                            m1 = mono_dec(g1); m2 = f2;
                            j1   = __builtin_amdgcn_readlane(ej, w);
                            disp = __builtin_amdgcn_readlane(candf, w);
                        }
                    }

                    if (!fast) {
                        // ---- dense scan (unchanged load/relax) ----
                        float4 c4[4];
                        if (USET) {
                            const float4* row =
                                (const float4*)(CbTB + (size_t)cur * Q);
                            #pragma unroll
                            for (int g = 0; g < 4; ++g) c4[g] = row[lane + 64 * g];
                        } else {
                            const float* col = CbB + cur;
                            #pragma unroll
                            for (int g = 0; g < 4; ++g) {
                                float* cf = (float*)&c4[g];
                                #pragma unroll
                                for (int e = 0; e < 4; ++e)
                                    cf[e] = col[(size_t)(256*g + 4*lane + e) * T];
                            }
                        }

                        float m1l = FINF, m2l = FINF; int j1l = 0;
                        #pragma unroll
                        for (int g = 0; g < 4; ++g) {
                            const float* cf = (const float*)&c4[g];
                            #pragma unroll
                            for (int e = 0; e < 4; ++e) {
                                const int k = 4 * g + e;
                                const int j = 256 * g + 4 * lane + e;
                                float r = cf[e] - ucur - v_[k];
                                if (r < m1l) { m2l = m1l; m1l = r; j1l = j; }
                                else if (r < m2l) { m2l = r; }
                            }
                        }

                        const int cand = row4col[j1l];   // speculative

                        // stage 1: exact min across the wave
                        const unsigned lm1 = mono_enc(m1l);
                        unsigned e1 = lm1;
                        DPP_UMIN_REDUCE(e1);
                        const unsigned g1 =
                            (unsigned)__builtin_amdgcn_readlane((int)e1, 63);
                        const unsigned long long bm = __ballot(lm1 == g1);
                        const int winner = __ffsll(bm) - 1;
                        // stage 2: exact multiset 2nd-min — winner contributes
                        // its local 2nd, everyone else their local 1st.
                        unsigned e2 = (lane == winner) ? mono_enc(m2l) : lm1;
                        DPP_UMIN_REDUCE(e2);
                        const unsigned g2 =
                            (unsigned)__builtin_amdgcn_readlane((int)e2, 63);
                        m1 = mono_dec(g1);
                        m2 = mono_dec(g2);
                        j1   = __builtin_amdgcn_readlane(j1l, winner);
                        disp = __builtin_amdgcn_readlane(cand, winner);
                    }

                    // dual update: u[cur] += m2 ; v[j1] -= (m2 - m1)
                    if (lane == 0) u_sh[cur] = ucur + m2;
                    if (((j1 >> 2) & 63) == lane) {
                        const int k = ((j1 >> 8) << 2) | (j1 & 3);
                        v_[k] -= (m2 - m1);
                        if (USET) v_lds[j1] = v_[k];   // bit-exact mirror
                    }

                    // steal j1
                    if (lane == 0) {
                        row4col[j1]  = cur;
                        col4row[cur] = j1;
                        if (disp >= 0) col4row[disp] = -1;
                    }
                    if (disp < 0) { cur = -1; break; }
                    cur = disp;
                }
                // if chain guard exhausted, 'cur' stays unmatched -> Dijkstra
            }
        }
    }

    // unmatched-row bitmasks for Dijkstra (ascending order)
    unsigned long long um0 = ~__ballot(col4row[lane] >= 0);
    unsigned long long um1 = ~__ballot(col4row[lane + 64] >= 0);

    for (int half = 0; half < 2; ++half) {
        unsigned long long mask = half ? um1 : um0;
        while (mask) {
            const int curRow = __ffsll(mask) - 1 + 64 * half;
            mask &= mask - 1;

            // ---- 1-hop fast exit: argmin column over the top-64 list; if
            // it is provably the global argmin AND free, augment directly.
            bool done0 = false;
            if (USET) {
                const float  ui = u_sh[curRow];
                const float  s0 = 0.0f - ui;
                const float2 te = top_lds[curRow * KTOP + lane];
                const int    ej = __float_as_int(te.y);
                const float  vv = v_lds[ej];
                const float  rr = (s0 + te.x) - vv;   // == dense expr
                const unsigned key = mono_enc(rr);
                const int ownf = row4col[ej];          // speculative
                unsigned rm = key;
                DPP_UMIN_REDUCE(rm);
                const unsigned g =
                    (unsigned)__builtin_amdgcn_readlane((int)rm, 63);
                const float lim = s0 + tau_lds[curRow];
                const float mv  = mono_dec(g);
                if (mv < lim) {   // list min beats every non-list column
                    const unsigned long long bm = __ballot(key == g);
                    const int w = __ffsll(bm) - 1;
                    const int jstar = __builtin_amdgcn_readlane(ej, w);
                    const int ra    = __builtin_amdgcn_readlane(ownf, w);
                    if (ra == -1) {
                        if (lane == 0) {
                            u_sh[curRow]    = ui + mv;
                            row4col[jstar]  = curRow;
                            col4row[curRow] = jstar;
                        }
                        done0 = true;
                    }
                }
            }
            if (done0) { __syncthreads(); continue; }

            #pragma unroll
            for (int k = 0; k < 16; ++k) dist_[k] = FINF;
            unsigned used  = 0;          // SC bitmask, bit k
            float    minVal = 0.0f;
            int      i_s  = curRow;
            int      sink = -1;
            int      cnt  = 0;

            for (int guard = 0; guard <= M; ++guard) {
                const float ui = u_sh[i_s];
                const float s  = minVal - ui;

                float4 c4[4];
                if (USET) {
                    const float4* row = (const float4*)(CbTB + (size_t)i_s * Q);
                    #pragma unroll
                    for (int g = 0; g < 4; ++g) c4[g] = row[lane + 64 * g];
                } else {
                    const float* col = CbB + i_s;
                    #pragma unroll
                    for (int g = 0; g < 4; ++g) {
                        float* cf = (float*)&c4[g];
                        #pragma unroll
                        for (int e = 0; e < 4; ++e)
                            cf[e] = col[(size_t)(256 * g + 4 * lane + e) * T];
                    }
                }

                // relax free columns + per-lane argmin
                float lmin = FINF; int lidx = 0;
                #pragma unroll
                for (int g = 0; g < 4; ++g) {
                    const float* cf = (const float*)&c4[g];
                    #pragma unroll
                    for (int e = 0; e < 4; ++e) {
                        const int k = 4 * g + e;
                        const int j = 256 * g + 4 * lane + e;
                        const bool fr = ((used >> k) & 1u) == 0u;
                        float r = s + cf[e] - v_[k];
                        if (fr && r < dist_[k]) {
                            dist_[k] = r;
                            path_lds[256 * g + 64 * e + lane] = i_s;  // swizzled
                        }
                        float a = fr ? dist_[k] : FINF;
                        if (a < lmin) { lmin = a; lidx = j; }
                    }
                }

                // speculative owner lookup (hides row4col LDS latency)
                const int cand = row4col[lidx];

                unsigned lmono = mono_enc(lmin);
                unsigned rmin = lmono;
                DPP_UMIN_REDUCE(rmin);
                const unsigned gmin =
                    (unsigned)__builtin_amdgcn_readlane((int)rmin, 63);

                const unsigned long long bmask = __ballot(lmono == gmin);
                const int winner = __ffsll(bmask) - 1;

                minVal = __uint_as_float(
                    (unsigned)__builtin_amdgcn_readlane(
                        (int)__float_as_uint(lmin), winner));
                const int jstar = __builtin_amdgcn_readlane(lidx, winner);

                if (((jstar >> 2) & 63) == lane)
                    used |= (1u << (((jstar >> 8) << 2) | (jstar & 3)));

                const int ra = __builtin_amdgcn_readlane(cand, winner);
                if (ra == -1) { sink = jstar; break; }
                if (lane == 0 && cnt < NR) { SRr[cnt] = ra; SRd[cnt] = minVal; }
                cnt++;
                i_s = ra;
            }

            // dual updates (scipy style, out of loop) + v_lds mirror
            #pragma unroll
            for (int k = 0; k < 16; ++k)
                if ((used >> k) & 1u) {
                    v_[k] += dist_[k] - minVal;
                    if (USET) v_lds[((k >> 2) << 8) + 4 * lane + (k & 3)] = v_[k];
                }

            if (lane == 0) u_sh[curRow] += minVal;
            for (int t = lane; t < cnt; t += 64)
                u_sh[SRr[t]] += minVal - SRd[t];

            // augment along path (serial, lane 0)
            if (lane == 0) {
                int j = sink;
                for (int g2 = 0; g2 < NR + 2; ++g2) {
                    int pi = path_lds[((j >> 8) << 8) | ((j & 3) << 6) |
                                      ((j >> 2) & 63)];
                    row4col[j] = pi;
                    int jn = col4row[pi];
                    col4row[pi] = j;
                    if (pi == curRow) break;
                    j = jn;
                }
            }
            __syncthreads();
        }
    }

    // output: rank(j) = #matched j' < j, via ballot prefix counts.
    int base = 0;
    #pragma unroll
    for (int g = 0; g < 4; ++g) {
        int tv[4], mt[4];
        #pragma unroll
        for (int e = 0; e < 4; ++e) {
            const int j = 256 * g + 4 * lane + e;
            tv[e] = row4col[j];
            mt[e] = (tv[e] >= 0);
        }
        unsigned long long B[4];
        #pragma unroll
        for (int e = 0; e < 4; ++e) B[e] = __ballot(mt[e] != 0);
        const unsigned long long low = (1ull << lane) - 1ull;
        int below = base;
        #pragma unroll
        for (int e = 0; e < 4; ++e) below += __popcll(B[e] & low);
        int local = 0;
        #pragma unroll
        for (int e = 0; e < 4; ++e) {
            if (mt[e]) {
                const int rank = below + local;
                const int j = 256 * g + 4 * lane + e;
                out_rows[b * NR + rank] = (float)j;
                out_cols[b * NR + rank] = (float)tv[e];
                ++local;
            }
        }
        #pragma unroll
        for (int e = 0; e < 4; ++e) base += __popcll(B[e]);
    }
}

// ---------------------------------------------------------------------------
extern "C" void kernel_launch(void* const* d_in, const int* in_sizes, int n_in,
                              void* d_out, int out_size, void* d_ws, size_t ws_size,
                              hipStream_t stream) {
    const float* logits = (const float*)d_in[0];
    const float* ppts   = (const float*)d_in[1];
    const int*   tlab   = (const int*)  d_in[2];
    const float* tpts   = (const float*)d_in[3];

    float* Cb   = (float*)d_out;                 // BS*Q*T floats
    float* rows = Cb + (size_t)BS * Q * T;       // BS*T floats
    float* cols = rows + (size_t)BS * T;         // BS*T floats

    float* CbT = (float*)d_ws;                               // 8 MiB
    const size_t cbtBytes  = (size_t)BS * NR * Q * sizeof(float);
    const size_t partBytes = (size_t)BS * NQB * NR * sizeof(unsigned long long);
    const size_t topkBytes = (size_t)BS * NR * KTOP * sizeof(float2);
    const size_t tauBytes  = (size_t)BS * NR * sizeof(float);

    unsigned long long* part = (unsigned long long*)((char*)d_ws + cbtBytes);
    float2* topk = (float2*)((char*)d_ws + cbtBytes + partBytes);
    float*  tau  = (float*) ((char*)d_ws + cbtBytes + partBytes + topkBytes);

    const size_t need = cbtBytes + partBytes + topkBytes + tauBytes;

    if (ws_size >= need) {
        prep_kernel<<<BS * NQB, 256, 0, stream>>>(logits, ppts, tlab, tpts,
                                                  Cb, CbT, part);
        topk_kernel<<<BS * NR / 4, 256, 0, stream>>>(CbT, topk, tau);
        solve_kernel<1><<<BS, 64, 0, stream>>>(Cb, CbT, part, topk, tau,
                                               rows, cols);
    } else {
        cost_kernel<<<4096, 256, 0, stream>>>(logits, ppts, tlab, tpts, Cb);
        solve_kernel<0><<<BS, 64, 0, stream>>>(Cb, CbT, nullptr, nullptr,
                                               nullptr, rows, cols);
    }
}

// Round 6
// 114.675 us; speedup vs baseline: 1.2046x; 1.2046x over previous
//
#include <hip/hip_runtime.h>
#include <hip/hip_bf16.h>
#include <math.h>

#define BS 16
#define Q 1024
#define CC 92
#define T 128
#define M 1024   // columns in transposed problem (= Q)
#define NR 128   // rows in transposed problem (= T)
#define NQB 16   // q-blocks of 64 per batch
#define KTOP 16  // per-row candidate list length (16 proven best; 64 regressed)

// ---------------------------------------------------------------------------
// Fused prep kernel: one block per (b, 64-q slab). Bit-identical Cb.
// ---------------------------------------------------------------------------
__global__ __launch_bounds__(256) void prep_kernel(
    const float* __restrict__ logits,   // [BS][Q][CC]
    const float* __restrict__ ppts,     // [BS][Q][2]
    const int*   __restrict__ tlab,     // [BS][T]
    const float* __restrict__ tpts,     // [BS][T][2]
    float* __restrict__ Cb,             // [BS][Q][T]
    float* __restrict__ CbT,            // [BS][NR][Q]
    unsigned long long* __restrict__ part)  // [BS][NQB][NR]
{
    const int blk = blockIdx.x;         // 0..BS*NQB-1
    const int b   = blk & 15;           // XCD swizzle: blk%8 == b%8
    const int qb  = blk >> 4;
    const int q0  = qb * 64;
    const int tid = threadIdx.x;
    const int lane = tid & 63;

    __shared__ float lg[64 * CC];       // logits slab, [ql][c]
    __shared__ float tile[128][68];     // [t][ql], pitch 68 for b128 align
    __shared__ float tx_sh[T], ty_sh[T];
    __shared__ int   lab_sh[T];
    __shared__ float mx_sh[64], inv_sh[64], px_sh[64], py_sh[64];

    if (tid < T) {
        lab_sh[tid] = tlab[b * T + tid];
        tx_sh[tid]  = tpts[(b * T + tid) * 2 + 0];
        ty_sh[tid]  = tpts[(b * T + tid) * 2 + 1];
    }
    if (tid < 64) {
        px_sh[tid] = ppts[((size_t)b * Q + q0 + tid) * 2 + 0];
        py_sh[tid] = ppts[((size_t)b * Q + q0 + tid) * 2 + 1];
    }
    const float* lbase = logits + ((size_t)b * Q + q0) * CC;
    for (int idx = tid; idx < 64 * CC; idx += 256) lg[idx] = lbase[idx];
    __syncthreads();

    // softmax stats: EXACT same op sequence as original cost kernel.
    {
        const int w = tid >> 6;
        for (int s = 0; s < 16; ++s) {
            const int ql = w * 16 + s;
            const float* c = &lg[ql * CC];
            float l0 = c[lane];
            float l1 = (lane + 64 < CC) ? c[lane + 64] : -INFINITY;
            float mx = fmaxf(l0, l1);
            #pragma unroll
            for (int off = 32; off > 0; off >>= 1)
                mx = fmaxf(mx, __shfl_down(mx, off));
            mx = __shfl(mx, 0);
            float es = expf(l0 - mx) + ((lane + 64 < CC) ? expf(l1 - mx) : 0.0f);
            #pragma unroll
            for (int off = 32; off > 0; off >>= 1) es += __shfl_down(es, off);
            es = __shfl(es, 0);
            if (lane == 0) { mx_sh[ql] = mx; inv_sh[ql] = 1.0f / es; }
        }
    }
    __syncthreads();

    // tile compute + Cb write: thread = (ql = tid>>2, tc = tid&3)
    {
        const int ql = tid >> 2;
        const int tc = tid & 3;
        const float px = px_sh[ql], py = py_sh[ql];
        const float mx = mx_sh[ql], inv = inv_sh[ql];
        const float* lgq = &lg[ql * CC];
        float* cbrow = Cb + ((size_t)b * Q + q0 + ql) * T + tc * 32;
        #pragma unroll
        for (int k = 0; k < 8; ++k) {
            float4 o;
            #pragma unroll
            for (int e = 0; e < 4; ++e) {
                const int t = tc * 32 + 4 * k + e;
                const int labv = lab_sh[t];
                float prob = expf(lgq[labv] - mx) * inv;
                float cp   = fabsf(px - tx_sh[t]) + fabsf(py - ty_sh[t]);
                float val  = cp - prob;
                (&o.x)[e] = val;
                tile[t][ql] = val;
            }
            ((float4*)cbrow)[k] = o;
        }
    }
    __syncthreads();

    // CbT write + rowmin partials: thread = (rg = tid>>4, c4 = tid&15)
    {
        const int rg = tid >> 4;
        const int c4 = tid & 15;
        #pragma unroll
        for (int it = 0; it < 8; ++it) {
            const int t = it * 16 + rg;
            float4 v = *(const float4*)&tile[t][4 * c4];
            *(float4*)(CbT + ((size_t)b * NR + t) * Q + q0 + 4 * c4) = v;

            unsigned long long bk = ~0ull;
            const float* vf = (const float*)&v;
            #pragma unroll
            for (int e = 0; e < 4; ++e) {
                unsigned bits = __float_as_uint(vf[e]);
                unsigned mono = (bits & 0x80000000u) ? ~bits
                                                     : (bits | 0x80000000u);
                const int j = q0 + 4 * c4 + e;
                unsigned long long key =
                    ((unsigned long long)mono << 10) | (unsigned)j;
                bk = (key < bk) ? key : bk;
            }
            #pragma unroll
            for (int off = 1; off < 16; off <<= 1) {
                unsigned long long ok = __shfl_xor(bk, off);
                bk = (ok < bk) ? ok : bk;
            }
            if (c4 == 0) part[((size_t)b * NQB + qb) * NR + t] = bk;
        }
    }
}

// ---------------------------------------------------------------------------
// Fallback cost kernel (only used if workspace is too small).
// ---------------------------------------------------------------------------
__global__ __launch_bounds__(256) void cost_kernel(
    const float* __restrict__ logits, const float* __restrict__ ppts,
    const int* __restrict__ tlab, const float* __restrict__ tpts,
    float* __restrict__ Cb)
{
    const int blk  = blockIdx.x;
    const int b    = blk >> 8;
    const int wave = threadIdx.x >> 6;
    const int lane = threadIdx.x & 63;
    const int q    = (blk & 255) * 4 + wave;

    __shared__ float tx_sh[T], ty_sh[T];
    __shared__ int   lab_sh[T];
    __shared__ float logit_sh[4][CC];

    if (threadIdx.x < T) {
        lab_sh[threadIdx.x] = tlab[b * T + threadIdx.x];
        tx_sh[threadIdx.x]  = tpts[(b * T + threadIdx.x) * 2 + 0];
        ty_sh[threadIdx.x]  = tpts[(b * T + threadIdx.x) * 2 + 1];
    }
    const float* lrow = logits + ((size_t)b * Q + q) * CC;
    float l0 = lrow[lane];
    float l1 = (lane + 64 < CC) ? lrow[lane + 64] : -INFINITY;
    logit_sh[wave][lane] = l0;
    if (lane + 64 < CC) logit_sh[wave][lane + 64] = l1;

    float mx = fmaxf(l0, l1);
    #pragma unroll
    for (int off = 32; off > 0; off >>= 1) mx = fmaxf(mx, __shfl_down(mx, off));
    mx = __shfl(mx, 0);
    float es = expf(l0 - mx) + ((lane + 64 < CC) ? expf(l1 - mx) : 0.0f);
    #pragma unroll
    for (int off = 32; off > 0; off >>= 1) es += __shfl_down(es, off);
    es = __shfl(es, 0);
    const float inv = 1.0f / es;
    const float px = ppts[((size_t)b * Q + q) * 2 + 0];
    const float py = ppts[((size_t)b * Q + q) * 2 + 1];
    __syncthreads();
    float* outrow = Cb + ((size_t)b * Q + q) * T;
    #pragma unroll
    for (int t = lane; t < T; t += 64) {
        int   labv = lab_sh[t];
        float prob = expf(logit_sh[wave][labv] - mx) * inv;
        float cp   = fabsf(px - tx_sh[t]) + fabsf(py - ty_sh[t]);
        outrow[t]  = cp - prob;
    }
}

// DPP wave64 umin reduce step: dest = min(x, x shifted by ctrl); OOB lanes
// keep old (= x), so they're no-ops. Self-merge is idempotent for pure min
// — this reduce is EXACT.
#define DPP_UMIN_STEP(x, ctrl)                                              \
    {                                                                       \
        unsigned _t = (unsigned)__builtin_amdgcn_update_dpp(                \
            (int)(x), (int)(x), (ctrl), 0xF, 0xF, false);                   \
        (x) = ((x) < _t) ? (x) : _t;                                        \
    }

#define DPP_UMIN_REDUCE(x)                                                  \
    DPP_UMIN_STEP(x, 0x111); DPP_UMIN_STEP(x, 0x112);                       \
    DPP_UMIN_STEP(x, 0x114); DPP_UMIN_STEP(x, 0x118);                       \
    DPP_UMIN_STEP(x, 0x142); DPP_UMIN_STEP(x, 0x143);

// 16-lane (row 0) variant: result valid in lane 15.
#define DPP_UMIN_REDUCE16(x)                                                \
    DPP_UMIN_STEP(x, 0x111); DPP_UMIN_STEP(x, 0x112);                       \
    DPP_UMIN_STEP(x, 0x114); DPP_UMIN_STEP(x, 0x118);

__device__ __forceinline__ unsigned mono_enc(float f) {
    unsigned b = __float_as_uint(f);
    return (b & 0x80000000u) ? ~b : (b | 0x80000000u);
}
__device__ __forceinline__ float mono_dec(unsigned m) {
    unsigned b = (m & 0x80000000u) ? (m ^ 0x80000000u) : ~m;
    return __uint_as_float(m & 0x80000000u ? (m ^ 0x80000000u) : ~m);
}

// (re-define cleanly to avoid any doubt about the expression above)
__device__ __forceinline__ float mono_dec2(unsigned m) {
    unsigned b = (m & 0x80000000u) ? (m ^ 0x80000000u) : ~m;
    return __uint_as_float(b);
}
#undef mono_dec
#define mono_dec mono_dec2

// ---------------------------------------------------------------------------
// topk kernel: one WAVE per (b, row). Builds the exact 16 smallest costs of
// each CbT row (by packed key (mono(c)&~1023)|j, i.e. 22 cost bits + 10 col
// bits) plus a provable threshold tau = bucket-floor of the 16th key:
// every column NOT in the list has c >= tau. Runs at full occupancy.
// ---------------------------------------------------------------------------
__global__ __launch_bounds__(256) void topk_kernel(
    const float* __restrict__ CbT,   // [BS*NR][Q]
    float2* __restrict__ topk,       // [BS*NR][KTOP] = (c, j-as-int)
    float* __restrict__ tauv)        // [BS*NR]
{
    const int wave = threadIdx.x >> 6;
    const int lane = threadIdx.x & 63;
    const int row  = blockIdx.x * 4 + wave;   // 0..BS*NR-1

    const float4* rp = (const float4*)(CbT + (size_t)row * Q);
    unsigned kk[16];
    #pragma unroll
    for (int g = 0; g < 4; ++g) {
        const float4 c4 = rp[lane + 64 * g];
        const float* cf = (const float*)&c4;
        #pragma unroll
        for (int e = 0; e < 4; ++e) {
            const int j = 256 * g + 4 * lane + e;
            kk[4 * g + e] = (mono_enc(cf[e]) & 0xFFFFFC00u) | (unsigned)j;
        }
    }

    // 16 rounds of global extract-min; lane r keeps the r-th smallest key.
    unsigned mykey = 0xFFFFFFFFu;
    #pragma unroll
    for (int r = 0; r < KTOP; ++r) {
        unsigned lm = kk[0];
        #pragma unroll
        for (int e = 1; e < 16; ++e) lm = (kk[e] < lm) ? kk[e] : lm;
        unsigned rm = lm;
        DPP_UMIN_REDUCE(rm);
        const unsigned g = (unsigned)__builtin_amdgcn_readlane((int)rm, 63);
        #pragma unroll
        for (int e = 0; e < 16; ++e) if (kk[e] == g) kk[e] = 0xFFFFFFFFu;
        if (lane == r) mykey = g;
    }

    if (lane < KTOP) {
        const int jj = (int)(mykey & 1023u);
        const float c = CbT[(size_t)row * Q + jj];   // exact fp32 cost
        topk[(size_t)row * KTOP + lane] = make_float2(c, __int_as_float(jj));
    }
    if (lane == KTOP - 1) tauv[row] = mono_dec(mykey & 0xFFFFFC00u);
}

// ---------------------------------------------------------------------------
// Kernel 2: JV solver. ONE WAVE per batch.
// Phase A: rowmin-greedy init. Phase B: ART with top-16 LDS fast path; the
// next chain row's (u, tau, list entry) are PREFETCHED before this step's
// dual-update writes and carried in registers — removes one serialized LDS
// round-trip per step. Prefetched addresses are immutable (top_lds,
// tau_lds) or untouched this step (u_sh[disp], disp != cur); v_lds /
// row4col reads stay in program order after the writes. Bit-identical
// values. Phase C: fp32 Dijkstra with 1-hop fast exit; dense otherwise.
// ---------------------------------------------------------------------------
template<int USET>
__global__ __launch_bounds__(64) void solve_kernel(
    const float* __restrict__ Cb,    // [BS][Q][T] fallback (strided)
    const float* __restrict__ CbT,   // [BS][NR][Q] row-major solver cost
    const unsigned long long* __restrict__ part,  // [BS][NQB][NR] or nullptr
    const float2* __restrict__ topk, // [BS][NR][KTOP] or nullptr
    const float* __restrict__ tauv,  // [BS][NR] or nullptr
    float* __restrict__ out_rows,    // [BS][T]
    float* __restrict__ out_cols)    // [BS][T]
{
    const int b    = blockIdx.x;
    const int lane = threadIdx.x;    // 0..63

    __shared__ int    row4col[M];    // col j -> row (-1 free)
    __shared__ int    col4row[NR];   // row i -> col (-1 free)
    __shared__ float  u_sh[NR];
    __shared__ int    path_lds[M];   // swizzled: A(j) = 256g + 64e + L
    __shared__ int    SRr[NR];       // rows that joined SR (excl. curRow)
    __shared__ float  SRd[NR];       // dist at which they joined
    __shared__ int    minj_sh[NR];   // per-row argmin column
    __shared__ int    claim[M];      // col j -> lowest row claiming it
    __shared__ float2 top_lds[NR * KTOP];  // per-row candidate lists (16 KB)
    __shared__ float  v_lds[M];      // mirror of distributed v_ (fast path)
    __shared__ float  tau_lds[NR];   // per-row non-list lower bound

    const float* CbB  = Cb  + (size_t)b * Q * T;
    const float* CbTB = CbT + (size_t)b * NR * Q;

    for (int j = lane; j < M;  j += 64) { row4col[j] = -1; claim[j] = 0x7fffffff; }
    for (int i = lane; i < NR; i += 64) col4row[i] = -1;

    if (USET) {
        // vectorized list load: 2 entries (16B) per lane-iter
        const float4* tsrc4 = (const float4*)(topk + (size_t)b * NR * KTOP);
        float4* tdst4 = (float4*)top_lds;
        for (int i = lane; i < NR * KTOP / 2; i += 64) tdst4[i] = tsrc4[i];
        for (int j = lane; j < M; j += 64) v_lds[j] = 0.0f;
        for (int i = lane; i < NR; i += 64) tau_lds[i] = tauv[(size_t)b * NR + i];
    }

    // decode rowmin partials (coalesced: lane-consecutive in r)
    if (part) {
        #pragma unroll
        for (int r2 = 0; r2 < 2; ++r2) {
            const int r = lane + 64 * r2;
            const unsigned long long* pr = part + (size_t)b * NQB * NR + r;
            unsigned long long k = pr[0];
            #pragma unroll
            for (int i = 1; i < NQB; ++i) {
                unsigned long long o = pr[(size_t)i * NR];
                k = (o < k) ? o : k;
            }
            minj_sh[r] = (int)(k & 1023u);
            u_sh[r] = mono_dec((unsigned)(k >> 10));
        }
    } else {
        for (int i = lane; i < NR; i += 64) { minj_sh[i] = -1; u_sh[i] = 0.0f; }
    }
    __syncthreads();

    // greedy: lowest row index wins its argmin column
    if (part) {
        #pragma unroll
        for (int r2 = 0; r2 < 2; ++r2) {
            const int r = lane + 64 * r2;
            atomicMin(&claim[minj_sh[r]], r);
        }
        __syncthreads();
        #pragma unroll
        for (int r2 = 0; r2 < 2; ++r2) {
            const int r = lane + 64 * r2;
            const int mj = minj_sh[r];
            if (claim[mj] == r) { col4row[r] = mj; row4col[mj] = r; }
        }
        __syncthreads();
    }

    const float FINF = INFINITY;
    float v_[16], dist_[16];
    #pragma unroll
    for (int k = 0; k < 16; ++k) v_[k] = 0.0f;

    // ---------------- Phase B: augmenting row reduction ------------------
    {
        unsigned long long am0 = ~__ballot(col4row[lane] >= 0);
        unsigned long long am1 = ~__ballot(col4row[lane + 64] >= 0);
        for (int half = 0; half < 2; ++half) {
            unsigned long long mask = half ? am1 : am0;
            while (mask) {
                int cur = __ffsll(mask) - 1 + 64 * half;
                mask &= mask - 1;

                // chain-carried state (prefetched across steps)
                float  ucur = u_sh[cur];
                float  tcur = 0.0f;
                float2 te   = make_float2(0.0f, 0.0f);
                if (USET) {
                    tcur = tau_lds[cur];
                    te   = top_lds[cur * KTOP + (lane & 15)];
                }

                for (int step = 0; step < 48; ++step) {
                    float m1, m2; int j1, disp;
                    bool fast = false;

                    if (USET) {
                        // ---- top-16 LDS fast path ----
                        const int    ej = __float_as_int(te.y);
                        const float  vv = v_lds[ej];
                        const float  rr = (te.x - ucur) - vv;  // == dense expr
                        unsigned key = mono_enc(rr);
                        if (lane >= 16) key = 0xFFFFFFFFu;
                        const int candf = row4col[ej];         // speculative
                        // stage 1: exact min
                        unsigned e1 = key;
                        DPP_UMIN_REDUCE16(e1);
                        const unsigned g1 =
                            (unsigned)__builtin_amdgcn_readlane((int)e1, 15);
                        const unsigned long long bm = __ballot(key == g1);
                        const int w = __ffsll(bm) - 1;
                        // stage 2: exact 2nd-min (exclude the winner's entry)
                        unsigned e2 = (lane == w) ? 0xFFFFFFFFu : key;
                        DPP_UMIN_REDUCE16(e2);
                        const unsigned g2 =
                            (unsigned)__builtin_amdgcn_readlane((int)e2, 15);
                        const float lim = tcur - ucur;
                        const float f2  = mono_dec(g2);
                        if (f2 < lim) {   // non-list r >= lim > m2 >= m1
                            fast = true;
                            m1 = mono_dec(g1); m2 = f2;
                            j1   = __builtin_amdgcn_readlane(ej, w);
                            disp = __builtin_amdgcn_readlane(candf, w);
                        }
                    }

                    if (!fast) {
                        // ---- dense scan (unchanged load/relax) ----
                        float4 c4[4];
                        if (USET) {
                            const float4* row =
                                (const float4*)(CbTB + (size_t)cur * Q);
                            #pragma unroll
                            for (int g = 0; g < 4; ++g) c4[g] = row[lane + 64 * g];
                        } else {
                            const float* col = CbB + cur;
                            #pragma unroll
                            for (int g = 0; g < 4; ++g) {
                                float* cf = (float*)&c4[g];
                                #pragma unroll
                                for (int e = 0; e < 4; ++e)
                                    cf[e] = col[(size_t)(256*g + 4*lane + e) * T];
                            }
                        }

                        float m1l = FINF, m2l = FINF; int j1l = 0;
                        #pragma unroll
                        for (int g = 0; g < 4; ++g) {
                            const float* cf = (const float*)&c4[g];
                            #pragma unroll
                            for (int e = 0; e < 4; ++e) {
                                const int k = 4 * g + e;
                                const int j = 256 * g + 4 * lane + e;
                                float r = cf[e] - ucur - v_[k];
                                if (r < m1l) { m2l = m1l; m1l = r; j1l = j; }
                                else if (r < m2l) { m2l = r; }
                            }
                        }

                        const int cand = row4col[j1l];   // speculative

                        // stage 1: exact min across the wave
                        const unsigned lm1 = mono_enc(m1l);
                        unsigned e1 = lm1;
                        DPP_UMIN_REDUCE(e1);
                        const unsigned g1 =
                            (unsigned)__builtin_amdgcn_readlane((int)e1, 63);
                        const unsigned long long bm = __ballot(lm1 == g1);
                        const int winner = __ffsll(bm) - 1;
                        // stage 2: exact multiset 2nd-min — winner contributes
                        // its local 2nd, everyone else their local 1st.
                        unsigned e2 = (lane == winner) ? mono_enc(m2l) : lm1;
                        DPP_UMIN_REDUCE(e2);
                        const unsigned g2 =
                            (unsigned)__builtin_amdgcn_readlane((int)e2, 63);
                        m1 = mono_dec(g1);
                        m2 = mono_dec(g2);
                        j1   = __builtin_amdgcn_readlane(j1l, winner);
                        disp = __builtin_amdgcn_readlane(cand, winner);
                    }

                    // ---- prefetch next chain row's carried state (reads
                    // issue BEFORE this step's writes; nxt != cur when used)
                    const int nxt = (disp >= 0) ? disp : cur;
                    const float u_nxt = u_sh[nxt];
                    float  t_nxt = 0.0f;
                    float2 te_nxt = make_float2(0.0f, 0.0f);
                    if (USET) {
                        t_nxt  = tau_lds[nxt];
                        te_nxt = top_lds[nxt * KTOP + (lane & 15)];
                    }

                    // dual update: u[cur] += m2 ; v[j1] -= (m2 - m1)
                    if (lane == 0) u_sh[cur] = ucur + m2;
                    if (((j1 >> 2) & 63) == lane) {
                        const int k = ((j1 >> 8) << 2) | (j1 & 3);
                        v_[k] -= (m2 - m1);
                        if (USET) v_lds[j1] = v_[k];   // bit-exact mirror
                    }

                    // steal j1
                    if (lane == 0) {
                        row4col[j1]  = cur;
                        col4row[cur] = j1;
                        if (disp >= 0) col4row[disp] = -1;
                    }
                    if (disp < 0) { cur = -1; break; }
                    cur = disp; ucur = u_nxt; tcur = t_nxt; te = te_nxt;
                }
                // if chain guard exhausted, 'cur' stays unmatched -> Dijkstra
            }
        }
    }

    // unmatched-row bitmasks for Dijkstra (ascending order)
    unsigned long long um0 = ~__ballot(col4row[lane] >= 0);
    unsigned long long um1 = ~__ballot(col4row[lane + 64] >= 0);

    for (int half = 0; half < 2; ++half) {
        unsigned long long mask = half ? um1 : um0;
        while (mask) {
            const int curRow = __ffsll(mask) - 1 + 64 * half;
            mask &= mask - 1;

            // ---- 1-hop fast exit: argmin column over the top-16 list; if
            // it is provably the global argmin AND free, augment directly.
            bool done0 = false;
            if (USET) {
                const float  ui = u_sh[curRow];
                const float  s0 = 0.0f - ui;
                const float2 te = top_lds[curRow * KTOP + (lane & 15)];
                const int    ej = __float_as_int(te.y);
                const float  vv = v_lds[ej];
                const float  rr = (s0 + te.x) - vv;   // == dense expr
                unsigned key = mono_enc(rr);
                if (lane >= 16) key = 0xFFFFFFFFu;
                const int ownf = row4col[ej];          // speculative
                unsigned rm = key;
                DPP_UMIN_REDUCE16(rm);
                const unsigned g =
                    (unsigned)__builtin_amdgcn_readlane((int)rm, 15);
                const float lim = s0 + tau_lds[curRow];
                const float mv  = mono_dec(g);
                if (mv < lim) {   // list min beats every non-list column
                    const unsigned long long bm = __ballot(key == g);
                    const int w = __ffsll(bm) - 1;
                    const int jstar = __builtin_amdgcn_readlane(ej, w);
                    const int ra    = __builtin_amdgcn_readlane(ownf, w);
                    if (ra == -1) {
                        if (lane == 0) {
                            u_sh[curRow]    = ui + mv;
                            row4col[jstar]  = curRow;
                            col4row[curRow] = jstar;
                        }
                        done0 = true;
                    }
                }
            }
            if (done0) { __syncthreads(); continue; }

            #pragma unroll
            for (int k = 0; k < 16; ++k) dist_[k] = FINF;
            unsigned used  = 0;          // SC bitmask, bit k
            float    minVal = 0.0f;
            int      i_s  = curRow;
            int      sink = -1;
            int      cnt  = 0;

            for (int guard = 0; guard <= M; ++guard) {
                const float ui = u_sh[i_s];
                const float s  = minVal - ui;

                float4 c4[4];
                if (USET) {
                    const float4* row = (const float4*)(CbTB + (size_t)i_s * Q);
                    #pragma unroll
                    for (int g = 0; g < 4; ++g) c4[g] = row[lane + 64 * g];
                } else {
                    const float* col = CbB + i_s;
                    #pragma unroll
                    for (int g = 0; g < 4; ++g) {
                        float* cf = (float*)&c4[g];
                        #pragma unroll
                        for (int e = 0; e < 4; ++e)
                            cf[e] = col[(size_t)(256 * g + 4 * lane + e) * T];
                    }
                }

                // relax free columns + per-lane argmin
                float lmin = FINF; int lidx = 0;
                #pragma unroll
                for (int g = 0; g < 4; ++g) {
                    const float* cf = (const float*)&c4[g];
                    #pragma unroll
                    for (int e = 0; e < 4; ++e) {
                        const int k = 4 * g + e;
                        const int j = 256 * g + 4 * lane + e;
                        const bool fr = ((used >> k) & 1u) == 0u;
                        float r = s + cf[e] - v_[k];
                        if (fr && r < dist_[k]) {
                            dist_[k] = r;
                            path_lds[256 * g + 64 * e + lane] = i_s;  // swizzled
                        }
                        float a = fr ? dist_[k] : FINF;
                        if (a < lmin) { lmin = a; lidx = j; }
                    }
                }

                // speculative owner lookup (hides row4col LDS latency)
                const int cand = row4col[lidx];

                unsigned lmono = mono_enc(lmin);
                unsigned rmin = lmono;
                DPP_UMIN_REDUCE(rmin);
                const unsigned gmin =
                    (unsigned)__builtin_amdgcn_readlane((int)rmin, 63);

                const unsigned long long bmask = __ballot(lmono == gmin);
                const int winner = __ffsll(bmask) - 1;

                minVal = __uint_as_float(
                    (unsigned)__builtin_amdgcn_readlane(
                        (int)__float_as_uint(lmin), winner));
                const int jstar = __builtin_amdgcn_readlane(lidx, winner);

                if (((jstar >> 2) & 63) == lane)
                    used |= (1u << (((jstar >> 8) << 2) | (jstar & 3)));

                const int ra = __builtin_amdgcn_readlane(cand, winner);
                if (ra == -1) { sink = jstar; break; }
                if (lane == 0 && cnt < NR) { SRr[cnt] = ra; SRd[cnt] = minVal; }
                cnt++;
                i_s = ra;
            }

            // dual updates (scipy style, out of loop) + v_lds mirror
            #pragma unroll
            for (int k = 0; k < 16; ++k)
                if ((used >> k) & 1u) {
                    v_[k] += dist_[k] - minVal;
                    if (USET) v_lds[((k >> 2) << 8) + 4 * lane + (k & 3)] = v_[k];
                }

            if (lane == 0) u_sh[curRow] += minVal;
            for (int t = lane; t < cnt; t += 64)
                u_sh[SRr[t]] += minVal - SRd[t];

            // augment along path (serial, lane 0)
            if (lane == 0) {
                int j = sink;
                for (int g2 = 0; g2 < NR + 2; ++g2) {
                    int pi = path_lds[((j >> 8) << 8) | ((j & 3) << 6) |
                                      ((j >> 2) & 63)];
                    row4col[j] = pi;
                    int jn = col4row[pi];
                    col4row[pi] = j;
                    if (pi == curRow) break;
                    j = jn;
                }
            }
            __syncthreads();
        }
    }

    // output: rank(j) = #matched j' < j, via ballot prefix counts.
    int base = 0;
    #pragma unroll
    for (int g = 0; g < 4; ++g) {
        int tv[4], mt[4];
        #pragma unroll
        for (int e = 0; e < 4; ++e) {
            const int j = 256 * g + 4 * lane + e;
            tv[e] = row4col[j];
            mt[e] = (tv[e] >= 0);
        }
        unsigned long long B[4];
        #pragma unroll
        for (int e = 0; e < 4; ++e) B[e] = __ballot(mt[e] != 0);
        const unsigned long long low = (1ull << lane) - 1ull;
        int below = base;
        #pragma unroll
        for (int e = 0; e < 4; ++e) below += __popcll(B[e] & low);
        int local = 0;
        #pragma unroll
        for (int e = 0; e < 4; ++e) {
            if (mt[e]) {
                const int rank = below + local;
                const int j = 256 * g + 4 * lane + e;
                out_rows[b * NR + rank] = (float)j;
                out_cols[b * NR + rank] = (float)tv[e];
                ++local;
            }
        }
        #pragma unroll
        for (int e = 0; e < 4; ++e) base += __popcll(B[e]);
    }
}

// ---------------------------------------------------------------------------
extern "C" void kernel_launch(void* const* d_in, const int* in_sizes, int n_in,
                              void* d_out, int out_size, void* d_ws, size_t ws_size,
                              hipStream_t stream) {
    const float* logits = (const float*)d_in[0];
    const float* ppts   = (const float*)d_in[1];
    const int*   tlab   = (const int*)  d_in[2];
    const float* tpts   = (const float*)d_in[3];

    float* Cb   = (float*)d_out;                 // BS*Q*T floats
    float* rows = Cb + (size_t)BS * Q * T;       // BS*T floats
    float* cols = rows + (size_t)BS * T;         // BS*T floats

    float* CbT = (float*)d_ws;                               // 8 MiB
    const size_t cbtBytes  = (size_t)BS * NR * Q * sizeof(float);
    const size_t partBytes = (size_t)BS * NQB * NR * sizeof(unsigned long long);
    const size_t topkBytes = (size_t)BS * NR * KTOP * sizeof(float2);
    const size_t tauBytes  = (size_t)BS * NR * sizeof(float);

    unsigned long long* part = (unsigned long long*)((char*)d_ws + cbtBytes);
    float2* topk = (float2*)((char*)d_ws + cbtBytes + partBytes);
    float*  tau  = (float*) ((char*)d_ws + cbtBytes + partBytes + topkBytes);

    const size_t need = cbtBytes + partBytes + topkBytes + tauBytes;

    if (ws_size >= need) {
        prep_kernel<<<BS * NQB, 256, 0, stream>>>(logits, ppts, tlab, tpts,
                                                  Cb, CbT, part);
        topk_kernel<<<BS * NR / 4, 256, 0, stream>>>(CbT, topk, tau);
        solve_kernel<1><<<BS, 64, 0, stream>>>(Cb, CbT, part, topk, tau,
                                               rows, cols);
    } else {
        cost_kernel<<<4096, 256, 0, stream>>>(logits, ppts, tlab, tpts, Cb);
        solve_kernel<0><<<BS, 64, 0, stream>>>(Cb, CbT, nullptr, nullptr,
                                               nullptr, rows, cols);
    }
}